// Round 6
// baseline (218.910 us; speedup 1.0000x reference)
//
#include <hip/hip_runtime.h>
#include <cmath>

#define B_ 16384
#define S_ 512
#define P_ 1024
#define K_ 8
#define D_ 64
#define H_ 128
#define BT 16    // batch rows per block
#define PADU 10  // LDS row stride in u32 (40 B): start bank 10*g%32 -> 16 phases; 20 KB tile

// float -> bf16 (RNE, finite inputs) packed helpers
static __device__ __forceinline__ unsigned int rne16(float f) {
  unsigned int u = __float_as_uint(f);
  return (u + 0x7fffu + ((u >> 16) & 1u)) >> 16;
}
static __device__ __forceinline__ float bflo(unsigned int u) { return __uint_as_float(u << 16); }
static __device__ __forceinline__ float bfhi(unsigned int u) { return __uint_as_float(u & 0xffff0000u); }

// ---------------- Kernel A: sklproj[s][h] = dot(skl_emd[s,:], U[h,:]) ----------------
__global__ __launch_bounds__(128) void proj_skl_kernel(
    const float* __restrict__ skl_emd, const float* __restrict__ U,
    float* __restrict__ sklproj) {
  __shared__ float row[D_];
  const int s = blockIdx.x, h = threadIdx.x;
  if (h < D_) row[h] = skl_emd[s * D_ + h];
  __syncthreads();
  float acc = 0.f;
#pragma unroll
  for (int d = 0; d < D_; d++) acc += row[d] * U[h * D_ + d];
  sklproj[s * H_ + h] = acc;
}

// ---------------- Kernel B: att[p][k] = softmax_k( sum_h v[h]*tanh(projP[p][h]+sklproj[g[p][k]][h]) )
__global__ __launch_bounds__(128) void att_kernel(
    const float* __restrict__ plm_emd, const float* __restrict__ W,
    const float* __restrict__ vT, const float* __restrict__ sklproj,
    const int* __restrict__ gidx, float* __restrict__ att) {
  __shared__ float prow[D_];
  __shared__ float red[2][K_];
  const int p = blockIdx.x, h = threadIdx.x;
  if (h < D_) prow[h] = plm_emd[p * D_ + h];
  __syncthreads();
  float pp = 0.f;
#pragma unroll
  for (int d = 0; d < D_; d++) pp += prow[d] * W[h * D_ + d];
  const float v = vT[h];
  int g[K_];
#pragma unroll
  for (int k = 0; k < K_; k++) g[k] = gidx[p * K_ + k];
  float partial[K_];
#pragma unroll
  for (int k = 0; k < K_; k++) partial[k] = v * tanhf(pp + sklproj[g[k] * H_ + h]);
#pragma unroll
  for (int off = 32; off >= 1; off >>= 1)
#pragma unroll
    for (int k = 0; k < K_; k++) partial[k] += __shfl_down(partial[k], off, 64);
  const int wave = h >> 6, lane = h & 63;
  if (lane == 0)
#pragma unroll
    for (int k = 0; k < K_; k++) red[wave][k] = partial[k];
  __syncthreads();
  if (h == 0) {
    float s[K_], m = -1e30f;
#pragma unroll
    for (int k = 0; k < K_; k++) { s[k] = red[0][k] + red[1][k]; m = fmaxf(m, s[k]); }
    float denom = 0.f;
#pragma unroll
    for (int k = 0; k < K_; k++) { s[k] = expf(s[k] - m); denom += s[k]; }
    const float inv = 1.f / denom;
#pragma unroll
    for (int k = 0; k < K_; k++) att[p * K_ + k] = s[k] * inv;
  }
}

// ---------------- Kernel C: out[b][p] = mask[b][p] * sum_k skl_pfc[b][g[p][k]] * att[p][k]
// Transposed LDS tile in PACKED BF16: rowsT[s][q] holds bb=2q (lo16) and bb=2q+1 (hi16).
// One (p,k) gather = 2x ds_read_b128 covering all 16 batch rows (8 values/instr) ->
// half the LDS gather instructions of the fp32 version. 20 KB tile; launch_bounds
// (256,6) -> ~85 VGPR cap (no spills), 6 blocks/CU.
__global__ __launch_bounds__(256, 6) void out_kernel(
    const float* __restrict__ skl_pfc, const float* __restrict__ mask,
    const float* __restrict__ att, const int* __restrict__ gidx,
    float* __restrict__ out) {
  __shared__ __align__(16) unsigned int rowsT[S_][PADU];  // 512*10*4 = 20480 B
  const int t = threadIdx.x;
  const int b0 = blockIdx.x * BT;

  // stage transposed + bf16-pack: s = t, t+256; per s read 16 batch values (coalesced
  // across t for each bb), pack pairs, 2x ds_write_b128.
#pragma unroll
  for (int i = 0; i < S_ / 256; i++) {
    const int s = t + i * 256;
    unsigned int pk[8];
#pragma unroll
    for (int q = 0; q < 8; q++) {
      const float f0 = skl_pfc[(size_t)(b0 + 2 * q) * S_ + s];
      const float f1 = skl_pfc[(size_t)(b0 + 2 * q + 1) * S_ + s];
      pk[q] = rne16(f0) | (rne16(f1) << 16);
    }
    *(uint4*)&rowsT[s][0] = make_uint4(pk[0], pk[1], pk[2], pk[3]);
    *(uint4*)&rowsT[s][4] = make_uint4(pk[4], pk[5], pk[6], pk[7]);
  }
  __syncthreads();

  for (int j = 0; j < 4; j++) {
    const int p = t + j * 256;
    const float4* ap = (const float4*)(att + (size_t)p * K_);
    const int4* gp = (const int4*)(gidx + (size_t)p * K_);
    const float4 a0 = ap[0], a1 = ap[1];
    const int4 g0 = gp[0], g1 = gp[1];
    const float av[K_] = {a0.x, a0.y, a0.z, a0.w, a1.x, a1.y, a1.z, a1.w};
    const int gv[K_] = {g0.x, g0.y, g0.z, g0.w, g1.x, g1.y, g1.z, g1.w};
    float m[BT];
#pragma unroll
    for (int bb = 0; bb < BT; bb++) m[bb] = mask[(size_t)(b0 + bb) * P_ + p];
    float acc[BT];
#pragma unroll
    for (int bb = 0; bb < BT; bb++) acc[bb] = 0.f;
#pragma unroll
    for (int k = 0; k < K_; k++) {
      const uint4 q0 = *(const uint4*)&rowsT[gv[k]][0];  // bb 0..7 packed
      const uint4 q1 = *(const uint4*)&rowsT[gv[k]][4];  // bb 8..15 packed
      const float a = av[k];
      acc[0]  += bflo(q0.x) * a; acc[1]  += bfhi(q0.x) * a;
      acc[2]  += bflo(q0.y) * a; acc[3]  += bfhi(q0.y) * a;
      acc[4]  += bflo(q0.z) * a; acc[5]  += bfhi(q0.z) * a;
      acc[6]  += bflo(q0.w) * a; acc[7]  += bfhi(q0.w) * a;
      acc[8]  += bflo(q1.x) * a; acc[9]  += bfhi(q1.x) * a;
      acc[10] += bflo(q1.y) * a; acc[11] += bfhi(q1.y) * a;
      acc[12] += bflo(q1.z) * a; acc[13] += bfhi(q1.z) * a;
      acc[14] += bflo(q1.w) * a; acc[15] += bfhi(q1.w) * a;
    }
#pragma unroll
    for (int bb = 0; bb < BT; bb++)
      out[(size_t)(b0 + bb) * P_ + p] = acc[bb] * m[bb];
  }
}

extern "C" void kernel_launch(void* const* d_in, const int* in_sizes, int n_in,
                              void* d_out, int out_size, void* d_ws, size_t ws_size,
                              hipStream_t stream) {
  const float* skl_pfc = (const float*)d_in[0];   // [B, S]
  const float* mask    = (const float*)d_in[1];   // [B, P]
  const float* skl_emd = (const float*)d_in[2];   // [S, D]
  const float* plm_emd = (const float*)d_in[3];   // [P, D]
  const float* W       = (const float*)d_in[4];   // [H, D]
  const float* U       = (const float*)d_in[5];   // [H, D]
  const float* vT      = (const float*)d_in[6];   // [1, H]
  const int*   gidx    = (const int*)d_in[7];     // [P, K]
  float* out = (float*)d_out;                     // [B, P]

  float* sklproj = (float*)d_ws;                  // S*H floats = 256 KB
  float* att     = sklproj + S_ * H_;             // P*K floats = 32 KB

  proj_skl_kernel<<<S_, 128, 0, stream>>>(skl_emd, U, sklproj);
  att_kernel<<<P_, 128, 0, stream>>>(plm_emd, W, vT, sklproj, gidx, att);
  out_kernel<<<B_ / BT, 256, 0, stream>>>(skl_pfc, mask, att, gidx, out);
}

// Round 7
// 172.913 us; speedup vs baseline: 1.2660x; 1.2660x over previous
//
#include <hip/hip_runtime.h>
#include <cmath>

#define B_ 16384
#define S_ 512
#define P_ 1024
#define K_ 8
#define D_ 64
#define H_ 128
#define BT 8     // batch rows per block; bf16-packed tile = 512*4*4B = 8 KB
#define PADU 4   // u32 per LDS row (4 u32 = 8 bf16 batch values), 16B-aligned for b128

// float -> bf16 (RNE, finite inputs) packed helpers
static __device__ __forceinline__ unsigned int rne16(float f) {
  unsigned int u = __float_as_uint(f);
  return (u + 0x7fffu + ((u >> 16) & 1u)) >> 16;
}
static __device__ __forceinline__ float bflo(unsigned int u) { return __uint_as_float(u << 16); }
static __device__ __forceinline__ float bfhi(unsigned int u) { return __uint_as_float(u & 0xffff0000u); }

// ---------------- Kernel A: sklproj[s][h] = dot(skl_emd[s,:], U[h,:]) ----------------
__global__ __launch_bounds__(128) void proj_skl_kernel(
    const float* __restrict__ skl_emd, const float* __restrict__ U,
    float* __restrict__ sklproj) {
  __shared__ float row[D_];
  const int s = blockIdx.x, h = threadIdx.x;
  if (h < D_) row[h] = skl_emd[s * D_ + h];
  __syncthreads();
  float acc = 0.f;
#pragma unroll
  for (int d = 0; d < D_; d++) acc += row[d] * U[h * D_ + d];
  sklproj[s * H_ + h] = acc;
}

// ---------------- Kernel B: att[p][k] = softmax_k( sum_h v[h]*tanh(projP[p][h]+sklproj[g[p][k]][h]) )
__global__ __launch_bounds__(128) void att_kernel(
    const float* __restrict__ plm_emd, const float* __restrict__ W,
    const float* __restrict__ vT, const float* __restrict__ sklproj,
    const int* __restrict__ gidx, float* __restrict__ att) {
  __shared__ float prow[D_];
  __shared__ float red[2][K_];
  const int p = blockIdx.x, h = threadIdx.x;
  if (h < D_) prow[h] = plm_emd[p * D_ + h];
  __syncthreads();
  float pp = 0.f;
#pragma unroll
  for (int d = 0; d < D_; d++) pp += prow[d] * W[h * D_ + d];
  const float v = vT[h];
  int g[K_];
#pragma unroll
  for (int k = 0; k < K_; k++) g[k] = gidx[p * K_ + k];
  float partial[K_];
#pragma unroll
  for (int k = 0; k < K_; k++) partial[k] = v * tanhf(pp + sklproj[g[k] * H_ + h]);
#pragma unroll
  for (int off = 32; off >= 1; off >>= 1)
#pragma unroll
    for (int k = 0; k < K_; k++) partial[k] += __shfl_down(partial[k], off, 64);
  const int wave = h >> 6, lane = h & 63;
  if (lane == 0)
#pragma unroll
    for (int k = 0; k < K_; k++) red[wave][k] = partial[k];
  __syncthreads();
  if (h == 0) {
    float s[K_], m = -1e30f;
#pragma unroll
    for (int k = 0; k < K_; k++) { s[k] = red[0][k] + red[1][k]; m = fmaxf(m, s[k]); }
    float denom = 0.f;
#pragma unroll
    for (int k = 0; k < K_; k++) { s[k] = expf(s[k] - m); denom += s[k]; }
    const float inv = 1.f / denom;
#pragma unroll
    for (int k = 0; k < K_; k++) att[p * K_ + k] = s[k] * inv;
  }
}

// ---------------- Kernel C: out[b][p] = mask[b][p] * sum_k skl_pfc[b][g[p][k]] * att[p][k]
// Transposed bf16-packed LDS tile: rowsT[s] = 4 u32 = 8 batch values. One (p,k)
// gather = ONE ds_read_b128 covering all 8 batch rows. 8 KB tile -> wave-capped
// 8 blocks/CU. NO min-waves launch bound: R4/R6 showed caps below ~64 VGPR force
// scratch spills (+50..125 MB HBM traffic).
__global__ __launch_bounds__(256) void out_kernel(
    const float* __restrict__ skl_pfc, const float* __restrict__ mask,
    const float* __restrict__ att, const int* __restrict__ gidx,
    float* __restrict__ out) {
  __shared__ __align__(16) unsigned int rowsT[S_][PADU];  // 8192 B
  const int t = threadIdx.x;
  const int b0 = blockIdx.x * BT;

  // stage transposed + bf16-pack: s = t, t+256; coalesced reads across lanes per bb
#pragma unroll
  for (int i = 0; i < S_ / 256; i++) {
    const int s = t + i * 256;
    unsigned int pk[PADU];
#pragma unroll
    for (int q = 0; q < PADU; q++) {
      const float f0 = skl_pfc[(size_t)(b0 + 2 * q) * S_ + s];
      const float f1 = skl_pfc[(size_t)(b0 + 2 * q + 1) * S_ + s];
      pk[q] = rne16(f0) | (rne16(f1) << 16);
    }
    *(uint4*)&rowsT[s][0] = make_uint4(pk[0], pk[1], pk[2], pk[3]);
  }
  __syncthreads();

  for (int j = 0; j < 4; j++) {
    const int p = t + j * 256;
    const float4* ap = (const float4*)(att + (size_t)p * K_);
    const int4* gp = (const int4*)(gidx + (size_t)p * K_);
    const float4 a0 = ap[0], a1 = ap[1];
    const int4 g0 = gp[0], g1 = gp[1];
    const float av[K_] = {a0.x, a0.y, a0.z, a0.w, a1.x, a1.y, a1.z, a1.w};
    const int gv[K_] = {g0.x, g0.y, g0.z, g0.w, g1.x, g1.y, g1.z, g1.w};
    float m[BT];
#pragma unroll
    for (int bb = 0; bb < BT; bb++) m[bb] = mask[(size_t)(b0 + bb) * P_ + p];
    float acc[BT] = {0.f, 0.f, 0.f, 0.f, 0.f, 0.f, 0.f, 0.f};
#pragma unroll
    for (int k = 0; k < K_; k++) {
      const uint4 q0 = *(const uint4*)&rowsT[gv[k]][0];  // bb 0..7 packed bf16
      const float a = av[k];
      acc[0] += bflo(q0.x) * a; acc[1] += bfhi(q0.x) * a;
      acc[2] += bflo(q0.y) * a; acc[3] += bfhi(q0.y) * a;
      acc[4] += bflo(q0.z) * a; acc[5] += bfhi(q0.z) * a;
      acc[6] += bflo(q0.w) * a; acc[7] += bfhi(q0.w) * a;
    }
#pragma unroll
    for (int bb = 0; bb < BT; bb++)
      out[(size_t)(b0 + bb) * P_ + p] = acc[bb] * m[bb];
  }
}

extern "C" void kernel_launch(void* const* d_in, const int* in_sizes, int n_in,
                              void* d_out, int out_size, void* d_ws, size_t ws_size,
                              hipStream_t stream) {
  const float* skl_pfc = (const float*)d_in[0];   // [B, S]
  const float* mask    = (const float*)d_in[1];   // [B, P]
  const float* skl_emd = (const float*)d_in[2];   // [S, D]
  const float* plm_emd = (const float*)d_in[3];   // [P, D]
  const float* W       = (const float*)d_in[4];   // [H, D]
  const float* U       = (const float*)d_in[5];   // [H, D]
  const float* vT      = (const float*)d_in[6];   // [1, H]
  const int*   gidx    = (const int*)d_in[7];     // [P, K]
  float* out = (float*)d_out;                     // [B, P]

  float* sklproj = (float*)d_ws;                  // S*H floats = 256 KB
  float* att     = sklproj + S_ * H_;             // P*K floats = 32 KB

  proj_skl_kernel<<<S_, 128, 0, stream>>>(skl_emd, U, sklproj);
  att_kernel<<<P_, 128, 0, stream>>>(plm_emd, W, vT, sklproj, gidx, att);
  out_kernel<<<B_ / BT, 256, 0, stream>>>(skl_pfc, mask, att, gidx, out);
}